// Round 7
// baseline (1165.486 us; speedup 1.0000x reference)
//
#include <hip/hip_runtime.h>
#include <hip/hip_bf16.h>
#include <stdint.h>

// B=512 L=32 E=2048 H=32 D=64 ; M = B*L = 16384 ; K = 2048 ; Nqkv = 6144
typedef __bf16 bf16x8 __attribute__((ext_vector_type(8)));
typedef float f32x4 __attribute__((ext_vector_type(4)));
typedef unsigned short u16x8 __attribute__((ext_vector_type(8)));
typedef unsigned short u16x4 __attribute__((ext_vector_type(4)));

#define G_AS __attribute__((address_space(1)))
#define L_AS __attribute__((address_space(3)))

__device__ __forceinline__ void gload_lds16(const void* g, void* l) {
  __builtin_amdgcn_global_load_lds((G_AS void*)g, (L_AS void*)l, 16, 0, 0);
}

__device__ __forceinline__ float b2f(unsigned short u) {
  union { float f; unsigned int i; } cv;
  cv.i = ((unsigned int)u) << 16;
  return cv.f;
}

__device__ __forceinline__ unsigned short f2b(float f) {
  unsigned int u = __float_as_uint(f);
  unsigned int r = u + 0x7FFFu + ((u >> 16) & 1u);  // RNE (inputs are non-NaN)
  return (unsigned short)(r >> 16);
}

// ---------------- cast / pack kernels ----------------

__global__ void k_cast_f32_bf16(const float* __restrict__ src,
                                unsigned short* __restrict__ dst, int n4) {
  int i = blockIdx.x * blockDim.x + threadIdx.x;
  if (i >= n4) return;
  float4 v = reinterpret_cast<const float4*>(src)[i];
  u16x4 o;
  o[0] = f2b(v.x); o[1] = f2b(v.y); o[2] = f2b(v.z); o[3] = f2b(v.w);
  reinterpret_cast<u16x4*>(dst)[i] = o;
}

// wqkvb rows: [0,2048)=wq, [2048,4096)=wk*0.125 (folds softmax scale), [4096,6144)=wv
__global__ void k_build_wqkv(const float* __restrict__ wq, const float* __restrict__ wk,
                             const float* __restrict__ wv, unsigned short* __restrict__ dst) {
  int i = blockIdx.x * blockDim.x + threadIdx.x;  // 6144*2048/4 = 3145728 threads
  if (i >= 3145728) return;
  int e = i << 2;
  int row = e >> 11;
  int col = e & 2047;
  const float* src; float sc = 1.0f;
  if (row < 2048) { src = wq + ((size_t)row << 11); }
  else if (row < 4096) { src = wk + ((size_t)(row - 2048) << 11); sc = 0.125f; }
  else { src = wv + ((size_t)(row - 4096) << 11); }
  float4 v = *reinterpret_cast<const float4*>(src + col);
  u16x4 o;
  o[0] = f2b(v.x * sc); o[1] = f2b(v.y * sc); o[2] = f2b(v.z * sc); o[3] = f2b(v.w * sc);
  *reinterpret_cast<u16x4*>(dst + e) = o;
}

__global__ void k_build_bqkv(const float* __restrict__ bq, const float* __restrict__ bk,
                             const float* __restrict__ bv, float* __restrict__ dst) {
  int i = blockIdx.x * blockDim.x + threadIdx.x;
  if (i >= 6144) return;
  float v;
  if (i < 2048) v = bq[i];
  else if (i < 4096) v = bk[i - 2048] * 0.125f;
  else v = bv[i - 4096];
  dst[i] = v;
}

// relb[h][j][d] = rpe[h - j + 31][d]   (faithful to the reference's H==L broadcast quirk)
__global__ void k_build_rel(const float* __restrict__ rpe, unsigned short* __restrict__ dst) {
  int i = blockIdx.x * blockDim.x + threadIdx.x;  // 32*32*16 = 16384
  if (i >= 16384) return;
  int h = i >> 9;
  int j = (i >> 4) & 31;
  int d = (i & 15) << 2;
  const float* s = rpe + (size_t)(h - j + 31) * 64 + d;
  float4 v = *reinterpret_cast<const float4*>(s);
  u16x4 o;
  o[0] = f2b(v.x); o[1] = f2b(v.y); o[2] = f2b(v.z); o[3] = f2b(v.w);
  *reinterpret_cast<u16x4*>(dst + ((size_t)i << 2)) = o;
}

// ---------------- GEMM: C[M][N] = A[M][K] * B[N][K]^T + bias[N] ----------------
// m97 structure (multi-block TLP, ~3 blocks/CU): 128x128 tile, BK=32, 4 waves (2x2),
// 256 threads, SINGLE 16 KiB LDS buffer, 2 __syncthreads per K-step (compiler drains
// vmcnt before the barrier), 16x16x32 MFMA, 4x4 frags/wave.
// + conflict-free chunked LDS layout (the round-1 -> round-7 delta; round 1 measured
//   5.0e7 SQ_LDS_BANK_CONFLICT with the naive row-major tile, this layout measures 0):
//   16B chunk for (row, slot) at phys = (row>>3)*32 + slot*8 + (row&7), slot = k/8.
//   A 16-lane frag read (rows r0..r0+15, fixed slot) sweeps all 32 banks exactly 2x.
// Staging: linear gload_lds dest chunk = tid (+256); global source permuted to match:
//   row = ((c>>5)<<3)|(c&7), col8 = (c>>3)&3   (inverse verified element-wise).

template <int OUT_F32>
__global__ __launch_bounds__(256)
void k_gemm128(const unsigned short* __restrict__ A,
               const unsigned short* __restrict__ B,
               const float* __restrict__ bias,
               void* __restrict__ Cptr,
               int M, int N, int K)
{
  __shared__ __align__(16) unsigned short As[4096];
  __shared__ __align__(16) unsigned short Bs[4096];

  const int nbn = N >> 7;
  const int bm = blockIdx.x / nbn;
  const int bn = blockIdx.x % nbn;

  const int tid = threadIdx.x;
  const int lane = tid & 63;
  const int wid = tid >> 6;
  const int wr = wid >> 1;   // 0..1
  const int wc = wid & 1;    // 0..1

  // staging: chunk c=tid covers rows 0..63, chunk c+256 covers rows 64..127
  const int rs = ((tid >> 5) << 3) + (tid & 7);   // 0..63
  const int cs = ((tid >> 3) & 3) << 3;           // 0,8,16,24
  const unsigned short* agA0 = A + (size_t)(bm * 128 + rs) * K + cs;
  const unsigned short* agA1 = agA0 + (size_t)64 * K;
  const unsigned short* agB0 = B + (size_t)(bn * 128 + rs) * K + cs;
  const unsigned short* agB1 = agB0 + (size_t)64 * K;
  const int ld0 = tid * 8;   // ushort index of chunk tid (byte = tid*16)

  // fragment read offsets: row = {wr|wc}*64 + i*16 + fr, slot q = lane>>4
  // ushort off = (row>>3)*256 + q*64 + (row&7)*8
  const int fr = lane & 15;
  const int q  = lane >> 4;
  const int rb = (fr >> 3) * 256 + q * 64 + (fr & 7) * 8;
  const int aOff = wr * 2048 + rb;   // + i*512
  const int bOff = wc * 2048 + rb;   // + j*512

  f32x4 acc[4][4] = {};

  for (int kt = 0; kt < K; kt += 32) {
    __syncthreads();
    gload_lds16(agA0 + kt, As + ld0);
    gload_lds16(agA1 + kt, As + ld0 + 2048);
    gload_lds16(agB0 + kt, Bs + ld0);
    gload_lds16(agB1 + kt, Bs + ld0 + 2048);
    __syncthreads();   // compiler drains vmcnt(0) before barrier -> tiles ready
    bf16x8 af[4], bfv[4];
#pragma unroll
    for (int i = 0; i < 4; ++i)
      af[i] = *reinterpret_cast<const bf16x8*>(As + aOff + i * 512);
#pragma unroll
    for (int j = 0; j < 4; ++j)
      bfv[j] = *reinterpret_cast<const bf16x8*>(Bs + bOff + j * 512);
#pragma unroll
    for (int i = 0; i < 4; ++i)
#pragma unroll
      for (int j = 0; j < 4; ++j)
        acc[i][j] = __builtin_amdgcn_mfma_f32_16x16x32_bf16(af[i], bfv[j], acc[i][j], 0, 0, 0);
  }

  // epilogue: C/D layout col = lane&15, row = (lane>>4)*4 + reg
  const int r0 = bm * 128 + wr * 64 + (q << 2);
  const int c0 = bn * 128 + wc * 64 + fr;
#pragma unroll
  for (int j = 0; j < 4; ++j) {
    const int col = c0 + j * 16;
    const float bv = bias[col];
#pragma unroll
    for (int i = 0; i < 4; ++i) {
#pragma unroll
      for (int r = 0; r < 4; ++r) {
        const int row = r0 + i * 16 + r;
        float v = acc[i][j][r] + bv;
        if (OUT_F32) {
          reinterpret_cast<float*>(Cptr)[(size_t)row * N + col] = v;
        } else {
          reinterpret_cast<unsigned short*>(Cptr)[(size_t)row * N + col] = f2b(v);
        }
      }
    }
  }
}

// ---------------- attention: one block (256 thr) per (b,h) ----------------
// qkv row-major [16384][6144]; q at col h*64, k(prescaled) at 2048+h*64, v at 4096+h*64
// S[i][j] = sum_d q[i,d]*(k_s[j,d] + rel[h,j,d]) ; softmax over j ; ctx = P·V

__global__ __launch_bounds__(256)
void k_attn(const unsigned short* __restrict__ qkv,
            const unsigned short* __restrict__ relb,
            unsigned short* __restrict__ ctx)
{
  __shared__ float qL[32][68];
  __shared__ float krL[32][68];
  __shared__ float vL[32][68];
  __shared__ float SL[32][33];

  const int bh = blockIdx.x;
  const int b = bh >> 5;
  const int h = bh & 31;
  const int t = threadIdx.x;
  const int r = t >> 3;           // row 0..31
  const int d0 = (t & 7) << 3;    // d 0..56 step 8

  const unsigned short* base = qkv + (size_t)(b * 32 + r) * 6144 + h * 64 + d0;
  u16x8 uq = *reinterpret_cast<const u16x8*>(base);
  u16x8 uk = *reinterpret_cast<const u16x8*>(base + 2048);
  u16x8 uv = *reinterpret_cast<const u16x8*>(base + 4096);
  u16x8 ur = *reinterpret_cast<const u16x8*>(relb + (((size_t)(h * 32 + r)) << 6) + d0);

  float fq[8], fkr[8], fv[8];
#pragma unroll
  for (int c = 0; c < 8; ++c) {
    fq[c] = b2f(uq[c]);
    fkr[c] = b2f(uk[c]) + b2f(ur[c]);
    fv[c] = b2f(uv[c]);
  }
  *reinterpret_cast<float4*>(&qL[r][d0])      = make_float4(fq[0], fq[1], fq[2], fq[3]);
  *reinterpret_cast<float4*>(&qL[r][d0 + 4])  = make_float4(fq[4], fq[5], fq[6], fq[7]);
  *reinterpret_cast<float4*>(&krL[r][d0])     = make_float4(fkr[0], fkr[1], fkr[2], fkr[3]);
  *reinterpret_cast<float4*>(&krL[r][d0 + 4]) = make_float4(fkr[4], fkr[5], fkr[6], fkr[7]);
  *reinterpret_cast<float4*>(&vL[r][d0])      = make_float4(fv[0], fv[1], fv[2], fv[3]);
  *reinterpret_cast<float4*>(&vL[r][d0 + 4])  = make_float4(fv[4], fv[5], fv[6], fv[7]);
  __syncthreads();

  const int i = r;
  const int j0 = (t & 7) << 2;   // 4 score cols per thread
  float s0 = 0.f, s1 = 0.f, s2 = 0.f, s3 = 0.f;
#pragma unroll
  for (int d = 0; d < 64; d += 4) {
    float4 qv = *reinterpret_cast<const float4*>(&qL[i][d]);
    float4 k0 = *reinterpret_cast<const float4*>(&krL[j0 + 0][d]);
    float4 k1 = *reinterpret_cast<const float4*>(&krL[j0 + 1][d]);
    float4 k2 = *reinterpret_cast<const float4*>(&krL[j0 + 2][d]);
    float4 k3 = *reinterpret_cast<const float4*>(&krL[j0 + 3][d]);
    s0 += qv.x * k0.x + qv.y * k0.y + qv.z * k0.z + qv.w * k0.w;
    s1 += qv.x * k1.x + qv.y * k1.y + qv.z * k1.z + qv.w * k1.w;
    s2 += qv.x * k2.x + qv.y * k2.y + qv.z * k2.z + qv.w * k2.w;
    s3 += qv.x * k3.x + qv.y * k3.y + qv.z * k3.z + qv.w * k3.w;
  }
  SL[i][j0 + 0] = s0; SL[i][j0 + 1] = s1; SL[i][j0 + 2] = s2; SL[i][j0 + 3] = s3;
  __syncthreads();

  float m = SL[i][0];
#pragma unroll
  for (int jj = 1; jj < 32; ++jj) m = fmaxf(m, SL[i][jj]);
  __syncthreads();  // all max reads done before P overwrites S

  float p0 = __expf(s0 - m), p1 = __expf(s1 - m), p2 = __expf(s2 - m), p3 = __expf(s3 - m);
  SL[i][j0 + 0] = p0; SL[i][j0 + 1] = p1; SL[i][j0 + 2] = p2; SL[i][j0 + 3] = p3;
  __syncthreads();

  float den = 0.f;
#pragma unroll
  for (int jj = 0; jj < 32; ++jj) den += SL[i][jj];
  const float inv = 1.0f / den;

  float o[8] = {0.f, 0.f, 0.f, 0.f, 0.f, 0.f, 0.f, 0.f};
#pragma unroll
  for (int jj = 0; jj < 32; ++jj) {
    float pj = SL[i][jj];
    float4 v0 = *reinterpret_cast<const float4*>(&vL[jj][d0]);
    float4 v1 = *reinterpret_cast<const float4*>(&vL[jj][d0 + 4]);
    o[0] += pj * v0.x; o[1] += pj * v0.y; o[2] += pj * v0.z; o[3] += pj * v0.w;
    o[4] += pj * v1.x; o[5] += pj * v1.y; o[6] += pj * v1.z; o[7] += pj * v1.w;
  }
  u16x8 ov;
#pragma unroll
  for (int c = 0; c < 8; ++c) ov[c] = f2b(o[c] * inv);
  *reinterpret_cast<u16x8*>(ctx + (size_t)(b * 32 + i) * 2048 + h * 64 + d0) = ov;
}

// ---------------- launch ----------------

extern "C" void kernel_launch(void* const* d_in, const int* in_sizes, int n_in,
                              void* d_out, int out_size, void* d_ws, size_t ws_size,
                              hipStream_t stream) {
  const float* x   = (const float*)d_in[0];
  const float* wq  = (const float*)d_in[1];
  const float* bq  = (const float*)d_in[2];
  const float* wk  = (const float*)d_in[3];
  const float* bk  = (const float*)d_in[4];
  const float* wv  = (const float*)d_in[5];
  const float* bv  = (const float*)d_in[6];
  const float* wo  = (const float*)d_in[7];
  const float* bo  = (const float*)d_in[8];
  const float* rpe = (const float*)d_in[9];

  char* ws = (char*)d_ws;
  unsigned short* xb    = (unsigned short*)(ws);
  unsigned short* wqkvb = (unsigned short*)(ws + 67108864);
  unsigned short* wob   = (unsigned short*)(ws + 67108864 + 25165824);
  unsigned short* qkvb  = (unsigned short*)(ws + 67108864 + 25165824 + 8388608);
  float*          bqkv  = (float*)(ws + 67108864 + 25165824 + 8388608 + 201326592);
  unsigned short* relb  = (unsigned short*)(ws + 67108864 + 25165824 + 8388608 + 201326592 + 24576);

  k_cast_f32_bf16<<<32768, 256, 0, stream>>>(x, xb, 8388608);          // 16384*2048/4
  k_build_wqkv<<<12288, 256, 0, stream>>>(wq, wk, wv, wqkvb);
  k_cast_f32_bf16<<<4096, 256, 0, stream>>>(wo, wob, 1048576);         // 2048*2048/4
  k_build_bqkv<<<24, 256, 0, stream>>>(bq, bk, bv, bqkv);
  k_build_rel<<<64, 256, 0, stream>>>(rpe, relb);

  // QKV projection: [16384][6144] = xb * wqkvb^T + bqkv  (bf16 out); grid 128x48
  k_gemm128<0><<<(16384 / 128) * (6144 / 128), 256, 0, stream>>>(
      xb, wqkvb, bqkv, qkvb, 16384, 6144, 2048);

  // attention -> ctx (reuses xb buffer)
  k_attn<<<16384, 256, 0, stream>>>(qkvb, relb, xb);

  // output projection: [16384][2048] = ctx * wob^T + bo  (fp32 out); grid 128x16
  k_gemm128<1><<<(16384 / 128) * (2048 / 128), 256, 0, stream>>>(
      xb, wob, bo, (float*)d_out, 16384, 2048, 2048);
}

// Round 8
// 786.832 us; speedup vs baseline: 1.4812x; 1.4812x over previous
//
#include <hip/hip_runtime.h>
#include <hip/hip_bf16.h>
#include <stdint.h>

// B=512 L=32 E=2048 H=32 D=64 ; M = B*L = 16384 ; K = 2048 ; Nqkv = 6144
typedef __bf16 bf16x8 __attribute__((ext_vector_type(8)));
typedef float f32x4 __attribute__((ext_vector_type(4)));
typedef unsigned short u16x8 __attribute__((ext_vector_type(8)));
typedef unsigned short u16x4 __attribute__((ext_vector_type(4)));

#define G_AS __attribute__((address_space(1)))
#define L_AS __attribute__((address_space(3)))

__device__ __forceinline__ void gload_lds16(const void* g, void* l) {
  __builtin_amdgcn_global_load_lds((G_AS void*)g, (L_AS void*)l, 16, 0, 0);
}

__device__ __forceinline__ float b2f(unsigned short u) {
  union { float f; unsigned int i; } cv;
  cv.i = ((unsigned int)u) << 16;
  return cv.f;
}

__device__ __forceinline__ unsigned short f2b(float f) {
  unsigned int u = __float_as_uint(f);
  unsigned int r = u + 0x7FFFu + ((u >> 16) & 1u);  // RNE (inputs are non-NaN)
  return (unsigned short)(r >> 16);
}

// ---------------- cast / pack kernels ----------------

__global__ void k_cast_f32_bf16(const float* __restrict__ src,
                                unsigned short* __restrict__ dst, int n4) {
  int i = blockIdx.x * blockDim.x + threadIdx.x;
  if (i >= n4) return;
  float4 v = reinterpret_cast<const float4*>(src)[i];
  u16x4 o;
  o[0] = f2b(v.x); o[1] = f2b(v.y); o[2] = f2b(v.z); o[3] = f2b(v.w);
  reinterpret_cast<u16x4*>(dst)[i] = o;
}

// wqkvb rows: [0,2048)=wq, [2048,4096)=wk*0.125 (folds softmax scale), [4096,6144)=wv
__global__ void k_build_wqkv(const float* __restrict__ wq, const float* __restrict__ wk,
                             const float* __restrict__ wv, unsigned short* __restrict__ dst) {
  int i = blockIdx.x * blockDim.x + threadIdx.x;  // 6144*2048/4 = 3145728 threads
  if (i >= 3145728) return;
  int e = i << 2;
  int row = e >> 11;
  int col = e & 2047;
  const float* src; float sc = 1.0f;
  if (row < 2048) { src = wq + ((size_t)row << 11); }
  else if (row < 4096) { src = wk + ((size_t)(row - 2048) << 11); sc = 0.125f; }
  else { src = wv + ((size_t)(row - 4096) << 11); }
  float4 v = *reinterpret_cast<const float4*>(src + col);
  u16x4 o;
  o[0] = f2b(v.x * sc); o[1] = f2b(v.y * sc); o[2] = f2b(v.z * sc); o[3] = f2b(v.w * sc);
  *reinterpret_cast<u16x4*>(dst + e) = o;
}

__global__ void k_build_bqkv(const float* __restrict__ bq, const float* __restrict__ bk,
                             const float* __restrict__ bv, float* __restrict__ dst) {
  int i = blockIdx.x * blockDim.x + threadIdx.x;
  if (i >= 6144) return;
  float v;
  if (i < 2048) v = bq[i];
  else if (i < 4096) v = bk[i - 2048] * 0.125f;
  else v = bv[i - 4096];
  dst[i] = v;
}

// relb[h][j][d] = rpe[h - j + 31][d]   (faithful to the reference's H==L broadcast quirk)
__global__ void k_build_rel(const float* __restrict__ rpe, unsigned short* __restrict__ dst) {
  int i = blockIdx.x * blockDim.x + threadIdx.x;  // 32*32*16 = 16384
  if (i >= 16384) return;
  int h = i >> 9;
  int j = (i >> 4) & 31;
  int d = (i & 15) << 2;
  const float* s = rpe + (size_t)(h - j + 31) * 64 + d;
  float4 v = *reinterpret_cast<const float4*>(s);
  u16x4 o;
  o[0] = f2b(v.x); o[1] = f2b(v.y); o[2] = f2b(v.z); o[3] = f2b(v.w);
  *reinterpret_cast<u16x4*>(dst + ((size_t)i << 2)) = o;
}

// ---------------- GEMM: C[M][N] = A[M][K] * B[N][K]^T + bias[N] ----------------
// Round-5 structure (best measured QKV: 537 us): 256x256 tile, 8 waves (2Mx4N),
// 512 threads, BK=32, 3-buffer LDS ring (96 KiB), fine 2-phase K-tile schedule,
// counted vmcnt(4) once per tile, setprio around MFMA, bm-major XCD swizzle.
//
// ROUND-8 DELTA (the only change): XOR-swizzled LDS layout instead of chunked
// permutation. LDS is row-major [256][32] ushort per matrix-buf, but the 16B
// slot within each 64B row is XORed:  slot' = s ^ ((row>>1)&3).
//  * staging: linear gload_lds dest (chunk c = row*4+s'); lane's GLOBAL col-slot
//    = (tid&3)^((tid>>3)&3) -> each 4-lane group still covers ONE contiguous 64B
//    line (permuted within the line) => round-1-class coalescing (the round-7
//    chunked layout scattered consecutive lanes 4KB apart and lost 40%).
//  * ds_read frag row = 16k+fr => XOR term = (fr>>1)&3 (lane constant sx); per
//    8-lane LDS phase the even lanes sweep slot-groups q^{0,1,2,3} => all 32
//    banks covered, <=2-way aliasing (free) vs round-1 row-major's 4-way (5e7).

template <int OUT_F32>
__global__ __launch_bounds__(512, 2)
void k_gemm256(const unsigned short* __restrict__ A,
               const unsigned short* __restrict__ B,
               const float* __restrict__ bias,
               void* __restrict__ Cptr,
               int M, int N, int K)
{
  __shared__ __align__(16) unsigned short As[3][8192];
  __shared__ __align__(16) unsigned short Bs[3][8192];

  // bijective XCD swizzle, bm-major
  const int nbn = N >> 8;
  const int cpx = gridDim.x >> 3;
  const int orig = blockIdx.x;
  const int wg = (orig & 7) * cpx + (orig >> 3);
  const int bm = wg / nbn;
  const int bn = wg % nbn;

  const int tid = threadIdx.x;
  const int lane = tid & 63;
  const int wid = tid >> 6;
  const int wr = wid >> 2;   // 0..1  (m-half)
  const int wc = wid & 3;    // 0..3  (64-col strip)

  // staging: chunk c=tid -> row tid>>2 (0..127), chunk c+512 -> row+128.
  // global col-slot is the XOR-swizzled one; 4 lanes of a row cover one 64B line.
  const int rs = tid >> 2;
  const int cs = ((tid & 3) ^ ((tid >> 3) & 3)) << 3;
  const unsigned short* agA0 = A + (size_t)(bm * 256 + rs) * K + cs;
  const unsigned short* agA1 = agA0 + (size_t)128 * K;   // (row+128)>>1 &3 unchanged
  const unsigned short* agB0 = B + (size_t)(bn * 256 + rs) * K + cs;
  const unsigned short* agB1 = agB0 + (size_t)128 * K;
  const int ldst = tid * 8;

  // fragment read offsets (ushort index inside one 8192-ushort matrix-buf)
  // row = {wr*128|wc*64} + {m|n}*16 + fr  ->  ushort row*32 + (q^((fr>>1)&3))*8
  const int fr = lane & 15;
  const int q  = lane >> 4;                       // k-slot 0..3
  const int sx = q ^ ((fr >> 1) & 3);             // swizzled slot (lane constant)
  const int rbase = fr * 32 + sx * 8;
  const int aOff = wr * 4096 + rbase;             // + m*512, m=0..7
  const int bOff = wc * 2048 + rbase;             // + n*512, n=0..3

  f32x4 acc[8][4] = {};
  const int NT = K >> 5;   // 64 K-tiles

  // prologue: stage tiles 0,1 into bufs 0,1
#pragma unroll
  for (int pf = 0; pf < 2; ++pf) {
    const int kof = pf << 5;
    gload_lds16(agA0 + kof, &As[pf][ldst]);
    gload_lds16(agA1 + kof, &As[pf][ldst + 4096]);
    gload_lds16(agB0 + kof, &Bs[pf][ldst]);
    gload_lds16(agB1 + kof, &Bs[pf][ldst + 4096]);
  }
  asm volatile("s_waitcnt vmcnt(4)" ::: "memory");   // tile 0 landed
  asm volatile("s_barrier" ::: "memory");

  int rb = 0;   // buf of tile t
  int sb = 2;   // buf of tile t+2
  for (int t = 0; t < NT; ++t) {
    const unsigned short* ab = &As[rb][0];
    const unsigned short* bb = &Bs[rb][0];
    const bool st = (t + 2) < NT;               // uniform
    const int kof = (t + 2) << 5;

    // ===== phase 0: A-low + B frags, stage A(t+2) =====
    bf16x8 afL[4], bf[4];
#pragma unroll
    for (int n = 0; n < 4; ++n)
      bf[n] = *reinterpret_cast<const bf16x8*>(bb + bOff + n * 512);
#pragma unroll
    for (int m = 0; m < 4; ++m)
      afL[m] = *reinterpret_cast<const bf16x8*>(ab + aOff + m * 512);
    if (st) {
      gload_lds16(agA0 + kof, &As[sb][ldst]);
      gload_lds16(agA1 + kof, &As[sb][ldst + 4096]);
    }
    __builtin_amdgcn_sched_barrier(0);
    asm volatile("s_barrier" ::: "memory");
    __builtin_amdgcn_sched_barrier(0);
    __builtin_amdgcn_s_setprio(1);
#pragma unroll
    for (int m = 0; m < 4; ++m)
#pragma unroll
      for (int n = 0; n < 4; ++n)
        acc[m][n] = __builtin_amdgcn_mfma_f32_16x16x32_bf16(afL[m], bf[n], acc[m][n], 0, 0, 0);
    __builtin_amdgcn_s_setprio(0);
    __builtin_amdgcn_sched_barrier(0);
    asm volatile("s_barrier" ::: "memory");

    // ===== phase 1: A-high frags, stage B(t+2), counted wait =====
    bf16x8 afH[4];
#pragma unroll
    for (int m = 0; m < 4; ++m)
      afH[m] = *reinterpret_cast<const bf16x8*>(ab + aOff + (4 + m) * 512);
    if (st) {
      gload_lds16(agB0 + kof, &Bs[sb][ldst]);
      gload_lds16(agB1 + kof, &Bs[sb][ldst + 4096]);
    }
    if (t < NT - 2)       asm volatile("s_waitcnt vmcnt(4)" ::: "memory");
    else if (t == NT - 2) asm volatile("s_waitcnt vmcnt(0)" ::: "memory");
    __builtin_amdgcn_sched_barrier(0);
    asm volatile("s_barrier" ::: "memory");
    __builtin_amdgcn_sched_barrier(0);
    __builtin_amdgcn_s_setprio(1);
#pragma unroll
    for (int m = 0; m < 4; ++m)
#pragma unroll
      for (int n = 0; n < 4; ++n)
        acc[4 + m][n] = __builtin_amdgcn_mfma_f32_16x16x32_bf16(afH[m], bf[n], acc[4 + m][n], 0, 0, 0);
    __builtin_amdgcn_s_setprio(0);
    __builtin_amdgcn_sched_barrier(0);
    asm volatile("s_barrier" ::: "memory");

    rb = (rb == 2) ? 0 : rb + 1;
    sb = (sb == 2) ? 0 : sb + 1;
  }

  // epilogue: C/D layout col = lane&15, row = (lane>>4)*4 + reg
  const int rBase = bm * 256 + wr * 128 + (q << 2);
  const int cBase = bn * 256 + wc * 64 + fr;
#pragma unroll
  for (int n = 0; n < 4; ++n) {
    const int col = cBase + n * 16;
    const float bv = bias[col];
#pragma unroll
    for (int m = 0; m < 8; ++m) {
      const int row = rBase + m * 16;
#pragma unroll
      for (int r = 0; r < 4; ++r) {
        float v = acc[m][n][r] + bv;
        if (OUT_F32) {
          reinterpret_cast<float*>(Cptr)[(size_t)(row + r) * N + col] = v;
        } else {
          reinterpret_cast<unsigned short*>(Cptr)[(size_t)(row + r) * N + col] = f2b(v);
        }
      }
    }
  }
}

// ---------------- attention: one block (256 thr) per (b,h) ----------------

__global__ __launch_bounds__(256)
void k_attn(const unsigned short* __restrict__ qkv,
            const unsigned short* __restrict__ relb,
            unsigned short* __restrict__ ctx)
{
  __shared__ float qL[32][68];
  __shared__ float krL[32][68];
  __shared__ float vL[32][68];
  __shared__ float SL[32][33];

  const int bh = blockIdx.x;
  const int b = bh >> 5;
  const int h = bh & 31;
  const int t = threadIdx.x;
  const int r = t >> 3;           // row 0..31
  const int d0 = (t & 7) << 3;    // d 0..56 step 8

  const unsigned short* base = qkv + (size_t)(b * 32 + r) * 6144 + h * 64 + d0;
  u16x8 uq = *reinterpret_cast<const u16x8*>(base);
  u16x8 uk = *reinterpret_cast<const u16x8*>(base + 2048);
  u16x8 uv = *reinterpret_cast<const u16x8*>(base + 4096);
  u16x8 ur = *reinterpret_cast<const u16x8*>(relb + (((size_t)(h * 32 + r)) << 6) + d0);

  float fq[8], fkr[8], fv[8];
#pragma unroll
  for (int c = 0; c < 8; ++c) {
    fq[c] = b2f(uq[c]);
    fkr[c] = b2f(uk[c]) + b2f(ur[c]);
    fv[c] = b2f(uv[c]);
  }
  *reinterpret_cast<float4*>(&qL[r][d0])      = make_float4(fq[0], fq[1], fq[2], fq[3]);
  *reinterpret_cast<float4*>(&qL[r][d0 + 4])  = make_float4(fq[4], fq[5], fq[6], fq[7]);
  *reinterpret_cast<float4*>(&krL[r][d0])     = make_float4(fkr[0], fkr[1], fkr[2], fkr[3]);
  *reinterpret_cast<float4*>(&krL[r][d0 + 4]) = make_float4(fkr[4], fkr[5], fkr[6], fkr[7]);
  *reinterpret_cast<float4*>(&vL[r][d0])      = make_float4(fv[0], fv[1], fv[2], fv[3]);
  *reinterpret_cast<float4*>(&vL[r][d0 + 4])  = make_float4(fv[4], fv[5], fv[6], fv[7]);
  __syncthreads();

  const int i = r;
  const int j0 = (t & 7) << 2;   // 4 score cols per thread
  float s0 = 0.f, s1 = 0.f, s2 = 0.f, s3 = 0.f;
#pragma unroll
  for (int d = 0; d < 64; d += 4) {
    float4 qv = *reinterpret_cast<const float4*>(&qL[i][d]);
    float4 k0 = *reinterpret_cast<const float4*>(&krL[j0 + 0][d]);
    float4 k1 = *reinterpret_cast<const float4*>(&krL[j0 + 1][d]);
    float4 k2 = *reinterpret_cast<const float4*>(&krL[j0 + 2][d]);
    float4 k3 = *reinterpret_cast<const float4*>(&krL[j0 + 3][d]);
    s0 += qv.x * k0.x + qv.y * k0.y + qv.z * k0.z + qv.w * k0.w;
    s1 += qv.x * k1.x + qv.y * k1.y + qv.z * k1.z + qv.w * k1.w;
    s2 += qv.x * k2.x + qv.y * k2.y + qv.z * k2.z + qv.w * k2.w;
    s3 += qv.x * k3.x + qv.y * k3.y + qv.z * k3.z + qv.w * k3.w;
  }
  SL[i][j0 + 0] = s0; SL[i][j0 + 1] = s1; SL[i][j0 + 2] = s2; SL[i][j0 + 3] = s3;
  __syncthreads();

  float m = SL[i][0];
#pragma unroll
  for (int jj = 1; jj < 32; ++jj) m = fmaxf(m, SL[i][jj]);
  __syncthreads();  // all max reads done before P overwrites S

  float p0 = __expf(s0 - m), p1 = __expf(s1 - m), p2 = __expf(s2 - m), p3 = __expf(s3 - m);
  SL[i][j0 + 0] = p0; SL[i][j0 + 1] = p1; SL[i][j0 + 2] = p2; SL[i][j0 + 3] = p3;
  __syncthreads();

  float den = 0.f;
#pragma unroll
  for (int jj = 0; jj < 32; ++jj) den += SL[i][jj];
  const float inv = 1.0f / den;

  float o[8] = {0.f, 0.f, 0.f, 0.f, 0.f, 0.f, 0.f, 0.f};
#pragma unroll
  for (int jj = 0; jj < 32; ++jj) {
    float pj = SL[i][jj];
    float4 v0 = *reinterpret_cast<const float4*>(&vL[jj][d0]);
    float4 v1 = *reinterpret_cast<const float4*>(&vL[jj][d0 + 4]);
    o[0] += pj * v0.x; o[1] += pj * v0.y; o[2] += pj * v0.z; o[3] += pj * v0.w;
    o[4] += pj * v1.x; o[5] += pj * v1.y; o[6] += pj * v1.z; o[7] += pj * v1.w;
  }
  u16x8 ov;
#pragma unroll
  for (int c = 0; c < 8; ++c) ov[c] = f2b(o[c] * inv);
  *reinterpret_cast<u16x8*>(ctx + (size_t)(b * 32 + i) * 2048 + h * 64 + d0) = ov;
}

// ---------------- launch ----------------

extern "C" void kernel_launch(void* const* d_in, const int* in_sizes, int n_in,
                              void* d_out, int out_size, void* d_ws, size_t ws_size,
                              hipStream_t stream) {
  const float* x   = (const float*)d_in[0];
  const float* wq  = (const float*)d_in[1];
  const float* bq  = (const float*)d_in[2];
  const float* wk  = (const float*)d_in[3];
  const float* bk  = (const float*)d_in[4];
  const float* wv  = (const float*)d_in[5];
  const float* bv  = (const float*)d_in[6];
  const float* wo  = (const float*)d_in[7];
  const float* bo  = (const float*)d_in[8];
  const float* rpe = (const float*)d_in[9];

  char* ws = (char*)d_ws;
  unsigned short* xb    = (unsigned short*)(ws);
  unsigned short* wqkvb = (unsigned short*)(ws + 67108864);
  unsigned short* wob   = (unsigned short*)(ws + 67108864 + 25165824);
  unsigned short* qkvb  = (unsigned short*)(ws + 67108864 + 25165824 + 8388608);
  float*          bqkv  = (float*)(ws + 67108864 + 25165824 + 8388608 + 201326592);
  unsigned short* relb  = (unsigned short*)(ws + 67108864 + 25165824 + 8388608 + 201326592 + 24576);

  k_cast_f32_bf16<<<32768, 256, 0, stream>>>(x, xb, 8388608);          // 16384*2048/4
  k_build_wqkv<<<12288, 256, 0, stream>>>(wq, wk, wv, wqkvb);
  k_cast_f32_bf16<<<4096, 256, 0, stream>>>(wo, wob, 1048576);         // 2048*2048/4
  k_build_bqkv<<<24, 256, 0, stream>>>(bq, bk, bv, bqkv);
  k_build_rel<<<64, 256, 0, stream>>>(rpe, relb);

  // QKV projection: [16384][6144] = xb * wqkvb^T + bqkv  (bf16 out); grid 64x24=1536 (%8==0)
  k_gemm256<0><<<(16384 / 256) * (6144 / 256), 512, 0, stream>>>(
      xb, wqkvb, bqkv, qkvb, 16384, 6144, 2048);

  // attention -> ctx (reuses xb buffer)
  k_attn<<<16384, 256, 0, stream>>>(qkvb, relb, xb);

  // output projection: [16384][2048] = ctx * wob^T + bo  (fp32 out); grid 64x8=512 (%8==0)
  k_gemm256<1><<<(16384 / 256) * (2048 / 256), 512, 0, stream>>>(
      xb, wob, bo, (float*)d_out, 16384, 2048, 2048);
}